// Round 4
// baseline (783.311 us; speedup 1.0000x reference)
//
#include <hip/hip_runtime.h>
#include <hip/hip_bf16.h>
#include <hip/hip_fp16.h>
#include <math.h>

typedef __hip_bfloat16 bf16;
typedef __attribute__((ext_vector_type(8))) short short8;   // 8 bf16 (MFMA A/B frag)
typedef __attribute__((ext_vector_type(4))) float f32x4;    // MFMA C/D frag

// ---------------- helpers ----------------
__device__ __forceinline__ float wred(float v) {
  #pragma unroll
  for (int o = 32; o > 0; o >>= 1) v += __shfl_xor(v, o, 64);
  return v;
}
__device__ __forceinline__ float sigf(float x) { return 1.f / (1.f + expf(-x)); }

// ---------------- GEMM: 64x64 tile, BK=32, 4 waves, 16x16x32 bf16 MFMA ------
// C[M,N] = A[M,K] @ Bt[N,K]^T (+bias f32, epilogue mode).
// A cols [0,splitK) from A0, rest from A1; aF32: A is float (converted to bf16
// at staging), else A is bf16. Bt always bf16.
// frag maps (HW-verified): A/B elem (lane&15, (lane>>4)*8+j); C/D row=(lane>>4)*4+p, col=lane&15.
// modes: 0 = bf16 store (+relu) | 1 = GRU zr (z->f16 zh, r*h->bf16 rhb)
//        2 = GRU c (h = z*h + (1-z)*tanh(x) -> bf16 hsb)
__global__ __launch_bounds__(256)
void sgemm(const void* __restrict__ A0v, const void* __restrict__ A1v,
           int splitK, int lda0, int lda1, int aF32,
           const bf16* __restrict__ Bt, int ldb,
           const float* __restrict__ bias, int K,
           int mode, int relu,
           bf16* __restrict__ Cb, int ldc,
           __half* __restrict__ zh, bf16* __restrict__ rhb,
           bf16* __restrict__ hsb)
{
  __shared__ __align__(16) bf16 As[64 * 32];
  __shared__ __align__(16) bf16 Bs[64 * 32];

  const int tid  = threadIdx.x;
  const int wave = tid >> 6, lane = tid & 63;
  const int lm = lane & 15, q = lane >> 4;
  const int wm = (wave >> 1) * 32, wn = (wave & 1) * 32;
  const int bm = blockIdx.y * 64, bn = blockIdx.x * 64;
  const int srow = tid >> 2, sch = (tid & 3) * 8;   // one short8 per thread per tile

  f32x4 acc[2][2];
  #pragma unroll
  for (int i = 0; i < 2; ++i)
    #pragma unroll
    for (int j = 0; j < 2; ++j) acc[i][j] = (f32x4){0.f, 0.f, 0.f, 0.f};

  for (int kb = 0; kb < K; kb += 32) {
    const void* Ap; int ldA, kc;
    if (kb < splitK) { Ap = A0v; ldA = lda0; kc = kb; }
    else             { Ap = A1v; ldA = lda1; kc = kb - splitK; }
    if (aF32) {
      const float* src = (const float*)Ap + (size_t)(bm + srow) * ldA + kc + sch;
      bf16 tmp[8];
      #pragma unroll
      for (int j = 0; j < 8; ++j) tmp[j] = __float2bfloat16(src[j]);
      *(short8*)(As + srow * 32 + sch) = *(const short8*)tmp;
    } else {
      *(short8*)(As + srow * 32 + sch) =
          *(const short8*)((const bf16*)Ap + (size_t)(bm + srow) * ldA + kc + sch);
    }
    *(short8*)(Bs + srow * 32 + sch) =
        *(const short8*)(Bt + (size_t)(bn + srow) * ldb + kb + sch);
    __syncthreads();

    short8 a0 = *(const short8*)(As + (wm + lm) * 32 + q * 8);
    short8 a1 = *(const short8*)(As + (wm + 16 + lm) * 32 + q * 8);
    short8 b0 = *(const short8*)(Bs + (wn + lm) * 32 + q * 8);
    short8 b1 = *(const short8*)(Bs + (wn + 16 + lm) * 32 + q * 8);
    acc[0][0] = __builtin_amdgcn_mfma_f32_16x16x32_bf16(a0, b0, acc[0][0], 0, 0, 0);
    acc[0][1] = __builtin_amdgcn_mfma_f32_16x16x32_bf16(a0, b1, acc[0][1], 0, 0, 0);
    acc[1][0] = __builtin_amdgcn_mfma_f32_16x16x32_bf16(a1, b0, acc[1][0], 0, 0, 0);
    acc[1][1] = __builtin_amdgcn_mfma_f32_16x16x32_bf16(a1, b1, acc[1][1], 0, 0, 0);
    __syncthreads();
  }

  #pragma unroll
  for (int i = 0; i < 2; ++i) {
    int row0 = bm + wm + i * 16 + q * 4;
    #pragma unroll
    for (int j = 0; j < 2; ++j) {
      int col = bn + wn + j * 16 + lm;
      float bv = bias[col];
      #pragma unroll
      for (int p = 0; p < 4; ++p) {
        int row = row0 + p;
        float x = acc[i][j][p] + bv;
        if (mode == 0) {
          if (relu) x = fmaxf(x, 0.f);
          Cb[(size_t)row * ldc + col] = __float2bfloat16(x);
        } else if (mode == 1) {
          float s = sigf(x);
          if (col < 512) {
            zh[(size_t)row * 512 + col] = __float2half(s);
          } else {
            size_t o = (size_t)row * 512 + (col - 512);
            rhb[o] = __float2bfloat16(s * (float)hsb[o]);
          }
        } else {
          size_t o = (size_t)row * 512 + col;
          float z = __half2float(zh[o]);
          float h = z * (float)hsb[o] + (1.f - z) * tanhf(x);
          hsb[o] = __float2bfloat16(h);
        }
      }
    }
  }
}

// ---------------- small kernels ----------------
// out[n*Ktot+k] = bf16( k<K0 ? X0[k*N+n] : X1[(k-K0)*N+n] )  (f32 in, bf16 out)
__global__ void tcat(const float* __restrict__ X0, const float* __restrict__ X1,
                     int K0, int Ktot, int N, bf16* __restrict__ out) {
  int i = blockIdx.x * 256 + threadIdx.x;
  if (i >= N * Ktot) return;
  int n = i / Ktot, k = i % Ktot;
  float v = (k < K0) ? X0[(size_t)k * N + n] : X1[(size_t)(k - K0) * N + n];
  out[i] = __float2bfloat16(v);
}

// l2norm rows of hsb -> Htr (f32), fused lv = sigmoid(Htr . W_leaf + b)
__global__ void norm_lvec(const bf16* __restrict__ hsb, const float* __restrict__ Wl,
                          const float* __restrict__ bl, float* __restrict__ Htr,
                          float* __restrict__ lv) {
  int w = threadIdx.x >> 6, lane = threadIdx.x & 63;
  int n = blockIdx.x * 4 + w;                       // grid 1024
  float x[8], ss = 0.f;
  #pragma unroll
  for (int j = 0; j < 8; ++j) {
    x[j] = (float)hsb[(size_t)n * 512 + lane * 8 + j];
    ss += x[j] * x[j];
  }
  ss = wred(ss);
  float inv = 1.f / fmaxf(sqrtf(ss), 1e-12f);
  float dot = 0.f;
  #pragma unroll
  for (int j = 0; j < 8; ++j) {
    float vv = x[j] * inv;
    Htr[(size_t)n * 512 + lane * 8 + j] = vv;
    dot += vv * Wl[lane * 8 + j];
  }
  dot = wred(dot);
  if (lane == 0) lv[n] = sigf(dot + bl[0]);
}

__global__ void hn_norm(const float* __restrict__ hv, float* __restrict__ hn) {
  int w = threadIdx.x >> 6, lane = threadIdx.x & 63; // block 256, grid 1
  float x[8], ss = 0.f;
  #pragma unroll
  for (int j = 0; j < 8; ++j) { x[j] = hv[w * 512 + lane * 8 + j]; ss += x[j] * x[j]; }
  ss = wred(ss);
  float inv = 1.f / fmaxf(sqrtf(ss), 1e-12f);
  #pragma unroll
  for (int j = 0; j < 8; ++j) hn[w * 512 + lane * 8 + j] = x[j] * inv;
}

__global__ void mkfinal(const float* __restrict__ xf, const float* __restrict__ Wc,
                        const float* __restrict__ bc, const float* __restrict__ lv,
                        float* __restrict__ fin) {
  int i = blockIdx.x * 256 + threadIdx.x;           // 16384
  int t = i >> 12, n = i & 4095;
  float g = bc[t];
  #pragma unroll
  for (int tt = 0; tt < 5; ++tt) g += xf[tt * 4096 + n] * Wc[tt * 4 + t];
  fin[i] = lv[n] * g;
}

// v[t,:] += Htr[chunk]^T * fin[t,chunk]   (Householder: W_t W_t^T = I drops out)
__global__ void htf(const float* __restrict__ Htr, const float* __restrict__ fin,
                    float* __restrict__ v) {
  int ch = blockIdx.x, t = blockIdx.y;              // grid (64,4), block 512
  int d = threadIdx.x;
  float s = 0.f;
  int n0 = ch * 64;
  for (int i = 0; i < 64; ++i)
    s += Htr[(size_t)(n0 + i) * 512 + d] * fin[t * 4096 + n0 + i];
  atomicAdd(&v[t * 512 + d], s);
}

__global__ void attk(const float* __restrict__ Htr, const float* __restrict__ v,
                     float* __restrict__ out) {
  int w = threadIdx.x >> 6, lane = threadIdx.x & 63;
  int gw = blockIdx.x * 4 + w;                      // grid 4096 -> 16384 waves
  int t = gw >> 12, n = gw & 4095;
  float s = 0.f;
  #pragma unroll
  for (int j = 0; j < 8; ++j)
    s += Htr[(size_t)n * 512 + lane * 8 + j] * v[t * 512 + lane * 8 + j];
  s = wred(s);
  if (lane == 0) out[gw] = s;
}

__global__ void loff(const float* __restrict__ Htr, const float* __restrict__ hn,
                     const int* __restrict__ ty, float* __restrict__ accum) {
  int w = threadIdx.x >> 6, lane = threadIdx.x & 63;
  int t = blockIdx.y;
  int m = blockIdx.x * 4 + w;                       // grid (512,4)
  const int* row = ty + ((size_t)t * 2048 + m) * 18;
  int pi = row[1];
  float p[8], hv[8], c = 0.f;
  #pragma unroll
  for (int j = 0; j < 8; ++j) {
    p[j]  = Htr[(size_t)pi * 512 + lane * 8 + j];
    hv[j] = hn[t * 512 + lane * 8 + j];
    c += p[j] * hv[j];
  }
  c = wred(c);
  float a[8], sp = 0.f;
  #pragma unroll
  for (int j = 0; j < 8; ++j) { a[j] = p[j] - 2.f * c * hv[j]; sp += a[j] * p[j]; }
  sp = wred(sp);
  float acc = 0.f;
  for (int k = 0; k < 16; ++k) {
    int ni = row[2 + k];
    float sn = 0.f;
    #pragma unroll
    for (int j = 0; j < 8; ++j) sn += a[j] * Htr[(size_t)ni * 512 + lane * 8 + j];
    sn = wred(sn);
    acc += fmaxf(sn - sp + 0.5f, 0.f);
  }
  if (lane == 0) atomicAdd(accum, acc);
}

__global__ void lleaf(const float* __restrict__ lv, const float* __restrict__ yl,
                      float* __restrict__ accum) {
  int i = blockIdx.x * 256 + threadIdx.x;           // 4096, grid 16
  float l = lv[i];
  float ym = 0.25f * (yl[i] + yl[4096 + i] + yl[8192 + i] + yl[12288 + i]);
  float term = fmaxf(l, 0.f) - l * ym + log1pf(expf(-fabsf(l)));
  float s = wred(term);
  __shared__ float sbuf[4];
  int w = threadIdx.x >> 6, lane = threadIdx.x & 63;
  if (lane == 0) sbuf[w] = s;
  __syncthreads();
  if (threadIdx.x == 0) atomicAdd(accum, sbuf[0] + sbuf[1] + sbuf[2] + sbuf[3]);
}

__global__ void fini(const float* __restrict__ acc2, float* __restrict__ out) {
  if (threadIdx.x == 0) {
    out[16384] = acc2[0] / (4.f * 2048.f * 16.f);
    out[16385] = acc2[1] / 4096.f;
  }
}

// ws_size diagnostic: absmax will read ~(1000 + ws_MB) if workspace too small
__global__ void wsprobe(float marker, float* out) {
  if (threadIdx.x == 0) out[0] = marker;
}

// ---------------- launch ----------------
extern "C" void kernel_launch(void* const* d_in, const int* in_sizes, int n_in,
                              void* d_out, int out_size, void* d_ws, size_t ws_size,
                              hipStream_t stream) {
  const float* x_feature   = (const float*)d_in[0];
  const float* x_graph     = (const float*)d_in[1];
  const float* x_graph_inv = (const float*)d_in[2];
  const int*   temp_y      = (const int*)d_in[3];
  const float* is_leaf     = (const float*)d_in[4];
  const float* W_gcn       = (const float*)d_in[5];
  const float* b_gcn       = (const float*)d_in[6];
  const float* Wx_zr       = (const float*)d_in[7];
  const float* Wh_zr       = (const float*)d_in[8];
  const float* b_zr        = (const float*)d_in[9];
  const float* Wx_c        = (const float*)d_in[10];
  const float* Wh_c        = (const float*)d_in[11];
  const float* b_c         = (const float*)d_in[12];
  const float* h_vecs      = (const float*)d_in[13];
  const float* W_leaf      = (const float*)d_in[14];
  const float* b_leaf      = (const float*)d_in[15];
  const float* W_conv      = (const float*)d_in[16];
  const float* b_conv      = (const float*)d_in[17];
  float* out = (float*)d_out;
  (void)in_sizes; (void)n_in; (void)out_size;

  const size_t NEED = 20087040;  // exact footprint (~19.2 MB); known to fit (R2 probe silent)
  if (ws_size < NEED) {
    wsprobe<<<1, 64, 0, stream>>>(1000.f + (float)(ws_size >> 20), out);
    return;
  }

  char* ws = (char*)d_ws;
  size_t off = 0;
  auto alloc = [&](size_t bytes) -> void* {
    void* p = ws + off;
    off = (off + bytes + 255) & ~(size_t)255;
    return p;
  };
  bf16*   W1t  = (bf16*)  alloc((size_t)1024 * 1024 * 2); // [[Wx_zr];[Wh_zr]]^T (N=1024,K=1024)
  bf16*   W2t  = (bf16*)  alloc((size_t)512 * 1024 * 2);  // [[Wx_c];[Wh_c]]^T   (N=512, K=1024)
  bf16*   Wgt  = (bf16*)  alloc((size_t)256 * 128 * 2);   // W_gcn^T             (N=256, K=128)
  bf16*   xtb  = (bf16*)  alloc((size_t)4096 * 512 * 2);  // h_final step t
  bf16*   rhb  = (bf16*)  alloc((size_t)4096 * 512 * 2);  // r*h (bf16)
  bf16*   hsb  = (bf16*)  alloc((size_t)4096 * 512 * 2);  // GRU state (bf16)
  __half* zh   = (__half*)alloc((size_t)4096 * 512 * 2);  // z gate (f16)
  float*  lv   = (float*) alloc(4096 * 4);
  float*  hn   = (float*) alloc(4 * 512 * 4);
  float*  fin  = (float*) alloc(4 * 4096 * 4);
  float*  v    = (float*) alloc(4 * 512 * 4);             // contiguous with acc2
  float*  acc2 = (float*) alloc(256);                     // [0]=loss_off, [1]=loss_leaf
  float*  Htr  = (float*) xtb;   // overlay: xtb+rhb (8 MB contiguous) dead after GRU loop

  hipMemsetAsync(hsb, 0, (size_t)4096 * 512 * 2, stream); // h0 = 0
  hipMemsetAsync(v, 0, 4 * 512 * 4 + 256, stream);        // v + acc2

  // weight transposes + f32->bf16 (once per launch)
  tcat<<<4096, 256, 0, stream>>>(Wx_zr, Wh_zr, 512, 1024, 1024, W1t);
  tcat<<<2048, 256, 0, stream>>>(Wx_c, Wh_c, 512, 1024, 512, W2t);
  tcat<<<128, 256, 0, stream>>>(W_gcn, W_gcn, 128, 128, 256, Wgt);

  // GRU over 8 steps; GCN recomputed per step (A = f32 x_graph)
  for (int t = 0; t < 8; ++t) {
    const float* xg  = x_graph     + (size_t)t * 4096 * 128;
    const float* xgi = x_graph_inv + (size_t)t * 4096 * 128;
    sgemm<<<dim3(4, 64), 256, 0, stream>>>(xg, xg, 128, 128, 128, 1, Wgt, 128,
        b_gcn, 128, 0, 1, xtb, 512, nullptr, nullptr, nullptr);
    sgemm<<<dim3(4, 64), 256, 0, stream>>>(xgi, xgi, 128, 128, 128, 1, Wgt, 128,
        b_gcn, 128, 0, 1, xtb + 256, 512, nullptr, nullptr, nullptr);
    sgemm<<<dim3(16, 64), 256, 0, stream>>>(xtb, hsb, 512, 512, 512, 0, W1t, 1024,
        b_zr, 1024, 1, 0, nullptr, 0, zh, rhb, hsb);
    sgemm<<<dim3(8, 64), 256, 0, stream>>>(xtb, rhb, 512, 512, 512, 0, W2t, 1024,
        b_c, 1024, 2, 0, nullptr, 0, zh, nullptr, hsb);
  }

  // epilogue chain (all f32)
  norm_lvec<<<1024, 256, 0, stream>>>(hsb, W_leaf, b_leaf, Htr, lv);
  hn_norm<<<1, 256, 0, stream>>>(h_vecs, hn);
  mkfinal<<<64, 256, 0, stream>>>(x_feature, W_conv, b_conv, lv, fin);
  htf<<<dim3(64, 4), 512, 0, stream>>>(Htr, fin, v);
  attk<<<4096, 256, 0, stream>>>(Htr, v, out);
  loff<<<dim3(512, 4), 256, 0, stream>>>(Htr, hn, temp_y, &acc2[0]);
  lleaf<<<16, 256, 0, stream>>>(lv, is_leaf, &acc2[1]);
  fini<<<1, 64, 0, stream>>>(acc2, out);
}

// Round 7
// 770.302 us; speedup vs baseline: 1.0169x; 1.0169x over previous
//
#include <hip/hip_runtime.h>
#include <hip/hip_bf16.h>
#include <hip/hip_fp16.h>
#include <math.h>

typedef __hip_bfloat16 bf16;
typedef __attribute__((ext_vector_type(8))) short short8;   // 8 bf16 (MFMA A/B frag)
typedef __attribute__((ext_vector_type(4))) float f32x4;    // MFMA C/D frag

// ---------------- helpers ----------------
__device__ __forceinline__ float wred(float v) {
  #pragma unroll
  for (int o = 32; o > 0; o >>= 1) v += __shfl_xor(v, o, 64);
  return v;
}
__device__ __forceinline__ float sigf(float x) { return 1.f / (1.f + expf(-x)); }

__device__ __forceinline__ void gl_lds16(const bf16* g, const bf16* lds) {
  // async global->LDS: lane i's 16B lands at wave-uniform LDS base + i*16
  __builtin_amdgcn_global_load_lds((const __attribute__((address_space(1))) void*)g,
                                   (__attribute__((address_space(3))) void*)lds,
                                   16, 0, 0);
}

// ---------------- GRU GEMM: 128x128 tile, BK=64, 4 waves, 16x16x32 MFMA -----
// C[M=4096, N] = A[.,K=1024] @ Bt[N,1024]^T + bias. A cols [0,512) from A0,
// [512,1024) from A1 (both bf16, ld 512). Bt bf16 [N,1024].
// LDS invariant: slot s of row r holds k-chunk s^(r&7) -> frag ds_read_b128
// 2-way aliased only (free). Staged via global_load_lds width=16 (verified
// correct: R5/R6 identical outputs with independent staging mechanics).
// mode 1 (zr): col<512 -> zh=f16(sigmoid); col>=512 -> rhb=bf16(sig*h)
// mode 2 (c):  h = z*h + (1-z)*tanh(x); hsb = bf16(h)
__global__ __launch_bounds__(256, 2)
void gru128(const bf16* __restrict__ A0, const bf16* __restrict__ A1,
            const bf16* __restrict__ Bt, int ldb,
            const float* __restrict__ bias, int mode,
            __half* __restrict__ zh, bf16* __restrict__ rhb,
            bf16* __restrict__ hsb)
{
  __shared__ __align__(16) bf16 As[128 * 64];
  __shared__ __align__(16) bf16 Bs[128 * 64];

  const int tid  = threadIdx.x;
  const int wave = tid >> 6, lane = tid & 63;
  const int lm = lane & 15, q = lane >> 4;
  const int brow = blockIdx.y, bcol = blockIdx.x;
  const int wr = (wave >> 1) * 64, wc = (wave & 1) * 64;
  const int srow = lane >> 3, sslot = lane & 7;

  f32x4 acc[4][4];
  #pragma unroll
  for (int i = 0; i < 4; ++i)
    #pragma unroll
    for (int j = 0; j < 4; ++j) acc[i][j] = (f32x4){0.f, 0.f, 0.f, 0.f};

  for (int kb = 0; kb < 1024; kb += 64) {
    const bf16* Ap = (kb < 512) ? A0 : A1;
    int kc = kb & 511;
    #pragma unroll
    for (int j = 0; j < 4; ++j) {
      int ml = wave * 32 + j * 8 + srow;           // tile row this lane fills
      int cg = sslot ^ (ml & 7);                   // swizzled source k-chunk
      gl_lds16(Ap + (size_t)(brow * 128 + ml) * 512 + kc + cg * 8,
               As + (wave * 4 + j) * 512);
      gl_lds16(Bt + (size_t)(bcol * 128 + ml) * ldb + kb + cg * 8,
               Bs + (wave * 4 + j) * 512);
    }
    __syncthreads();
    #pragma unroll
    for (int ks = 0; ks < 2; ++ks) {
      short8 af[4], bfr[4];
      #pragma unroll
      for (int i = 0; i < 4; ++i) {
        int cg = ks * 4 + q;                        // k-chunk this lane needs
        int ml = wr + i * 16 + lm;
        af[i]  = *(const short8*)(As + ml * 64 + ((cg ^ (ml & 7)) * 8));
        int nl = wc + i * 16 + lm;
        bfr[i] = *(const short8*)(Bs + nl * 64 + ((cg ^ (nl & 7)) * 8));
      }
      #pragma unroll
      for (int i = 0; i < 4; ++i)
        #pragma unroll
        for (int j = 0; j < 4; ++j)
          acc[i][j] = __builtin_amdgcn_mfma_f32_16x16x32_bf16(af[i], bfr[j], acc[i][j], 0, 0, 0);
    }
    __syncthreads();
  }

  // C/D map (R4-verified): row = q*4+p, col = lane&15
  #pragma unroll
  for (int i = 0; i < 4; ++i) {
    int row0 = brow * 128 + wr + i * 16 + q * 4;
    #pragma unroll
    for (int j = 0; j < 4; ++j) {
      int col = bcol * 128 + wc + j * 16 + lm;
      float bv = bias[col];
      #pragma unroll
      for (int p = 0; p < 4; ++p) {
        int row = row0 + p;
        float x = acc[i][j][p] + bv;
        if (mode == 1) {
          float s = sigf(x);
          if (col < 512) {
            zh[(size_t)row * 512 + col] = __float2half(s);
          } else {
            size_t o = (size_t)row * 512 + (col - 512);
            rhb[o] = __float2bfloat16(s * (float)hsb[o]);
          }
        } else {
          size_t o = (size_t)row * 512 + col;
          float z = __half2float(zh[o]);
          float h = z * (float)hsb[o] + (1.f - z) * tanhf(x);
          hsb[o] = __float2bfloat16(h);
        }
      }
    }
  }
}

// ---------------- GCN GEMM: f32 A, dual source via blockIdx.z ---------------
// out[:, z*256 + col] = relu(Az[4096,128] @ Wgt[256,128]^T + b_gcn), bf16.
// FIX (R5/R6 bug): weight row index is bcol*128+ml — NO cout offset (both z
// use the same W_gcn; cout applies only to the output columns).
__global__ __launch_bounds__(256, 2)
void gcn128(const float* __restrict__ Ag, const float* __restrict__ Agi,
            const bf16* __restrict__ Wgt, const float* __restrict__ bias,
            bf16* __restrict__ out)
{
  __shared__ __align__(16) bf16 As[128 * 64];
  __shared__ __align__(16) bf16 Bs[128 * 64];

  const int tid  = threadIdx.x;
  const int wave = tid >> 6, lane = tid & 63;
  const int lm = lane & 15, q = lane >> 4;
  const int brow = blockIdx.y, bcol = blockIdx.x;
  const int z = blockIdx.z, cout = z * 256;
  const float* A = z ? Agi : Ag;
  const int wr = (wave >> 1) * 64, wc = (wave & 1) * 64;
  const int srow = lane >> 3, sslot = lane & 7;

  f32x4 acc[4][4];
  #pragma unroll
  for (int i = 0; i < 4; ++i)
    #pragma unroll
    for (int j = 0; j < 4; ++j) acc[i][j] = (f32x4){0.f, 0.f, 0.f, 0.f};

  for (int kb = 0; kb < 128; kb += 64) {
    #pragma unroll
    for (int j = 0; j < 4; ++j) {
      int ml = wave * 32 + j * 8 + srow;
      int cg = sslot ^ (ml & 7);
      const float* src = A + (size_t)(brow * 128 + ml) * 128 + kb + cg * 8;
      bf16 tmp[8];
      #pragma unroll
      for (int e = 0; e < 8; ++e) tmp[e] = __float2bfloat16(src[e]);
      *(short8*)(As + ml * 64 + sslot * 8) = *(const short8*)tmp;
      gl_lds16(Wgt + (size_t)(bcol * 128 + ml) * 128 + kb + cg * 8,
               Bs + (wave * 4 + j) * 512);
    }
    __syncthreads();
    #pragma unroll
    for (int ks = 0; ks < 2; ++ks) {
      short8 af[4], bfr[4];
      #pragma unroll
      for (int i = 0; i < 4; ++i) {
        int cg = ks * 4 + q;
        int ml = wr + i * 16 + lm;
        af[i]  = *(const short8*)(As + ml * 64 + ((cg ^ (ml & 7)) * 8));
        int nl = wc + i * 16 + lm;
        bfr[i] = *(const short8*)(Bs + nl * 64 + ((cg ^ (nl & 7)) * 8));
      }
      #pragma unroll
      for (int i = 0; i < 4; ++i)
        #pragma unroll
        for (int j = 0; j < 4; ++j)
          acc[i][j] = __builtin_amdgcn_mfma_f32_16x16x32_bf16(af[i], bfr[j], acc[i][j], 0, 0, 0);
    }
    __syncthreads();
  }

  #pragma unroll
  for (int i = 0; i < 4; ++i) {
    int row0 = brow * 128 + wr + i * 16 + q * 4;
    #pragma unroll
    for (int j = 0; j < 4; ++j) {
      int col = bcol * 128 + wc + j * 16 + lm;
      float bv = bias[col];
      #pragma unroll
      for (int p = 0; p < 4; ++p) {
        float x = fmaxf(acc[i][j][p] + bv, 0.f);
        out[(size_t)(row0 + p) * 512 + cout + col] = __float2bfloat16(x);
      }
    }
  }
}

// ---------------- small kernels ----------------
__global__ void tcat(const float* __restrict__ X0, const float* __restrict__ X1,
                     int K0, int Ktot, int N, bf16* __restrict__ out) {
  int i = blockIdx.x * 256 + threadIdx.x;
  if (i >= N * Ktot) return;
  int n = i / Ktot, k = i % Ktot;
  float v = (k < K0) ? X0[(size_t)k * N + n] : X1[(size_t)(k - K0) * N + n];
  out[i] = __float2bfloat16(v);
}

// l2norm rows of hsb -> Htrb (bf16), fused lv = sigmoid(Htr . W_leaf + b)
__global__ void norm_lvec(const bf16* __restrict__ hsb, const float* __restrict__ Wl,
                          const float* __restrict__ bl, bf16* __restrict__ Htrb,
                          float* __restrict__ lv) {
  int w = threadIdx.x >> 6, lane = threadIdx.x & 63;
  int n = blockIdx.x * 4 + w;                       // grid 1024
  float x[8], ss = 0.f;
  #pragma unroll
  for (int j = 0; j < 8; ++j) {
    x[j] = (float)hsb[(size_t)n * 512 + lane * 8 + j];
    ss += x[j] * x[j];
  }
  ss = wred(ss);
  float inv = 1.f / fmaxf(sqrtf(ss), 1e-12f);
  float dot = 0.f;
  #pragma unroll
  for (int j = 0; j < 8; ++j) {
    float vv = x[j] * inv;
    Htrb[(size_t)n * 512 + lane * 8 + j] = __float2bfloat16(vv);
    dot += vv * Wl[lane * 8 + j];
  }
  dot = wred(dot);
  if (lane == 0) lv[n] = sigf(dot + bl[0]);
}

__global__ void hn_norm(const float* __restrict__ hv, float* __restrict__ hn) {
  int w = threadIdx.x >> 6, lane = threadIdx.x & 63; // block 256, grid 1
  float x[8], ss = 0.f;
  #pragma unroll
  for (int j = 0; j < 8; ++j) { x[j] = hv[w * 512 + lane * 8 + j]; ss += x[j] * x[j]; }
  ss = wred(ss);
  float inv = 1.f / fmaxf(sqrtf(ss), 1e-12f);
  #pragma unroll
  for (int j = 0; j < 8; ++j) hn[w * 512 + lane * 8 + j] = x[j] * inv;
}

__global__ void mkfinal(const float* __restrict__ xf, const float* __restrict__ Wc,
                        const float* __restrict__ bc, const float* __restrict__ lv,
                        float* __restrict__ fin) {
  int i = blockIdx.x * 256 + threadIdx.x;           // 16384
  int t = i >> 12, n = i & 4095;
  float g = bc[t];
  #pragma unroll
  for (int tt = 0; tt < 5; ++tt) g += xf[tt * 4096 + n] * Wc[tt * 4 + t];
  fin[i] = lv[n] * g;
}

// v[t,:] += Htrb[chunk]^T * fin[t,chunk], all 4 t per block (rows read once)
__global__ void htf(const bf16* __restrict__ Htrb, const float* __restrict__ fin,
                    float* __restrict__ v) {
  int ch = blockIdx.x;                              // grid 64, block 512
  int d = threadIdx.x;
  int n0 = ch * 64;
  float s0 = 0.f, s1 = 0.f, s2 = 0.f, s3 = 0.f;
  for (int i = 0; i < 64; ++i) {
    float hv = (float)Htrb[(size_t)(n0 + i) * 512 + d];
    s0 += hv * fin[n0 + i];
    s1 += hv * fin[4096 + n0 + i];
    s2 += hv * fin[8192 + n0 + i];
    s3 += hv * fin[12288 + n0 + i];
  }
  atomicAdd(&v[d], s0);
  atomicAdd(&v[512 + d], s1);
  atomicAdd(&v[1024 + d], s2);
  atomicAdd(&v[1536 + d], s3);
}

// att[t,n] = Htrb[n,:] . v[t,:] for all 4 t per wave (row read once)
__global__ void attk(const bf16* __restrict__ Htrb, const float* __restrict__ v,
                     float* __restrict__ out) {
  int w = threadIdx.x >> 6, lane = threadIdx.x & 63;
  int n = blockIdx.x * 4 + w;                       // grid 1024
  float x[8];
  #pragma unroll
  for (int j = 0; j < 8; ++j) x[j] = (float)Htrb[(size_t)n * 512 + lane * 8 + j];
  #pragma unroll
  for (int t = 0; t < 4; ++t) {
    float s = 0.f;
    #pragma unroll
    for (int j = 0; j < 8; ++j) s += x[j] * v[t * 512 + lane * 8 + j];
    s = wred(s);
    if (lane == 0) out[t * 4096 + n] = s;
  }
}

// triplet loss partials: loffp[t*512+bx] = block sum (no atomics)
__global__ void loff(const bf16* __restrict__ Htrb, const float* __restrict__ hn,
                     const int* __restrict__ ty, float* __restrict__ loffp) {
  int w = threadIdx.x >> 6, lane = threadIdx.x & 63;
  int t = blockIdx.y;
  int m = blockIdx.x * 4 + w;                       // grid (512,4)
  const int* row = ty + ((size_t)t * 2048 + m) * 18;
  int pi = row[1];
  float p[8], hv[8], c = 0.f;
  #pragma unroll
  for (int j = 0; j < 8; ++j) {
    p[j]  = (float)Htrb[(size_t)pi * 512 + lane * 8 + j];
    hv[j] = hn[t * 512 + lane * 8 + j];
    c += p[j] * hv[j];
  }
  c = wred(c);
  float a[8], sp = 0.f;
  #pragma unroll
  for (int j = 0; j < 8; ++j) { a[j] = p[j] - 2.f * c * hv[j]; sp += a[j] * p[j]; }
  sp = wred(sp);
  float acc = 0.f;
  for (int k = 0; k < 16; ++k) {
    int ni = row[2 + k];
    float sn = 0.f;
    #pragma unroll
    for (int j = 0; j < 8; ++j) sn += a[j] * (float)Htrb[(size_t)ni * 512 + lane * 8 + j];
    sn = wred(sn);
    acc += fmaxf(sn - sp + 0.5f, 0.f);
  }
  __shared__ float sbuf[4];
  if (lane == 0) sbuf[w] = acc;
  __syncthreads();
  if (threadIdx.x == 0)
    loffp[t * 512 + blockIdx.x] = sbuf[0] + sbuf[1] + sbuf[2] + sbuf[3];
}

__global__ void lleaf(const float* __restrict__ lv, const float* __restrict__ yl,
                      float* __restrict__ accum) {
  int i = blockIdx.x * 256 + threadIdx.x;           // 4096, grid 16
  float l = lv[i];
  float ym = 0.25f * (yl[i] + yl[4096 + i] + yl[8192 + i] + yl[12288 + i]);
  float term = fmaxf(l, 0.f) - l * ym + log1pf(expf(-fabsf(l)));
  float s = wred(term);
  __shared__ float sbuf[4];
  int w = threadIdx.x >> 6, lane = threadIdx.x & 63;
  if (lane == 0) sbuf[w] = s;
  __syncthreads();
  if (threadIdx.x == 0) atomicAdd(accum, sbuf[0] + sbuf[1] + sbuf[2] + sbuf[3]);
}

__global__ void fini(const float* __restrict__ loffp, const float* __restrict__ acc2,
                     float* __restrict__ out) {
  int tid = threadIdx.x, w = tid >> 6, lane = tid & 63;   // 1 block, 256 threads
  float s = 0.f;
  for (int i = tid; i < 2048; i += 256) s += loffp[i];
  s = wred(s);
  __shared__ float sb[4];
  if (lane == 0) sb[w] = s;
  __syncthreads();
  if (tid == 0) {
    out[16384] = (sb[0] + sb[1] + sb[2] + sb[3]) / (4.f * 2048.f * 16.f);
    out[16385] = acc2[1] / 4096.f;
  }
}

__global__ void wsprobe(float marker, float* out) {
  if (threadIdx.x == 0) out[0] = marker;
}

// ---------------- launch ----------------
extern "C" void kernel_launch(void* const* d_in, const int* in_sizes, int n_in,
                              void* d_out, int out_size, void* d_ws, size_t ws_size,
                              hipStream_t stream) {
  const float* x_feature   = (const float*)d_in[0];
  const float* x_graph     = (const float*)d_in[1];
  const float* x_graph_inv = (const float*)d_in[2];
  const int*   temp_y      = (const int*)d_in[3];
  const float* is_leaf     = (const float*)d_in[4];
  const float* W_gcn       = (const float*)d_in[5];
  const float* b_gcn       = (const float*)d_in[6];
  const float* Wx_zr       = (const float*)d_in[7];
  const float* Wh_zr       = (const float*)d_in[8];
  const float* b_zr        = (const float*)d_in[9];
  const float* Wx_c        = (const float*)d_in[10];
  const float* Wh_c        = (const float*)d_in[11];
  const float* b_c         = (const float*)d_in[12];
  const float* h_vecs      = (const float*)d_in[13];
  const float* W_leaf      = (const float*)d_in[14];
  const float* b_leaf      = (const float*)d_in[15];
  const float* W_conv      = (const float*)d_in[16];
  const float* b_conv      = (const float*)d_in[17];
  float* out = (float*)d_out;
  (void)in_sizes; (void)n_in; (void)out_size;

  const size_t NEED = 20095232;  // footprint; R4 confirmed this fits
  if (ws_size < NEED) {
    wsprobe<<<1, 64, 0, stream>>>(1000.f + (float)(ws_size >> 20), out);
    return;
  }

  char* ws = (char*)d_ws;
  size_t off = 0;
  auto alloc = [&](size_t bytes) -> void* {
    void* p = ws + off;
    off = (off + bytes + 255) & ~(size_t)255;
    return p;
  };
  bf16*   W1t   = (bf16*)  alloc((size_t)1024 * 1024 * 2); // [[Wx_zr];[Wh_zr]]^T (N=1024,K=1024)
  bf16*   W2t   = (bf16*)  alloc((size_t)512 * 1024 * 2);  // [[Wx_c];[Wh_c]]^T   (N=512, K=1024)
  bf16*   Wgt   = (bf16*)  alloc((size_t)256 * 128 * 2);   // W_gcn^T             (N=256, K=128)
  bf16*   xtb   = (bf16*)  alloc((size_t)4096 * 512 * 2);  // h_final step t; Htrb overlay after
  bf16*   rhb   = (bf16*)  alloc((size_t)4096 * 512 * 2);  // r*h (bf16)
  bf16*   hsb   = (bf16*)  alloc((size_t)4096 * 512 * 2);  // GRU state (bf16)
  __half* zh    = (__half*)alloc((size_t)4096 * 512 * 2);  // z gate (f16)
  float*  lv    = (float*) alloc(4096 * 4);
  float*  hn    = (float*) alloc(4 * 512 * 4);
  float*  fin   = (float*) alloc(4 * 4096 * 4);
  float*  v     = (float*) alloc(4 * 512 * 4);             // contiguous with acc2
  float*  acc2  = (float*) alloc(256);                     // [1]=loss_leaf sum
  float*  loffp = (float*) alloc(2048 * 4);                // loff block partials
  bf16*   Htrb  = xtb;   // overlay: xtb dead after GRU loop

  hipMemsetAsync(hsb, 0, (size_t)4096 * 512 * 2, stream); // h0 = 0
  hipMemsetAsync(v, 0, 4 * 512 * 4 + 256, stream);        // v + acc2

  // weight transposes + f32->bf16 (once per launch)
  tcat<<<4096, 256, 0, stream>>>(Wx_zr, Wh_zr, 512, 1024, 1024, W1t);
  tcat<<<2048, 256, 0, stream>>>(Wx_c, Wh_c, 512, 1024, 512, W2t);
  tcat<<<128, 256, 0, stream>>>(W_gcn, W_gcn, 128, 128, 256, Wgt);

  // GRU over 8 steps; GCN per step (dual-source z-trick, one launch)
  for (int t = 0; t < 8; ++t) {
    const float* xg  = x_graph     + (size_t)t * 4096 * 128;
    const float* xgi = x_graph_inv + (size_t)t * 4096 * 128;
    gcn128<<<dim3(2, 32, 2), 256, 0, stream>>>(xg, xgi, Wgt, b_gcn, xtb);
    gru128<<<dim3(8, 32), 256, 0, stream>>>(xtb, hsb, W1t, 1024, b_zr, 1, zh, rhb, hsb);
    gru128<<<dim3(4, 32), 256, 0, stream>>>(xtb, rhb, W2t, 1024, b_c, 2, zh, nullptr, hsb);
  }

  // epilogue chain
  norm_lvec<<<1024, 256, 0, stream>>>(hsb, W_leaf, b_leaf, Htrb, lv);
  hn_norm<<<1, 256, 0, stream>>>(h_vecs, hn);
  mkfinal<<<64, 256, 0, stream>>>(x_feature, W_conv, b_conv, lv, fin);
  htf<<<64, 512, 0, stream>>>(Htrb, fin, v);
  attk<<<1024, 256, 0, stream>>>(Htrb, v, out);
  loff<<<dim3(512, 4), 256, 0, stream>>>(Htrb, hn, temp_y, loffp);
  lleaf<<<16, 256, 0, stream>>>(lv, is_leaf, &acc2[1]);
  fini<<<1, 256, 0, stream>>>(loffp, acc2, out);
}

// Round 8
// 680.031 us; speedup vs baseline: 1.1519x; 1.1327x over previous
//
#include <hip/hip_runtime.h>
#include <hip/hip_bf16.h>
#include <hip/hip_fp16.h>
#include <math.h>

typedef __hip_bfloat16 bf16;
typedef __attribute__((ext_vector_type(8))) short short8;   // 8 bf16 (MFMA A/B frag)
typedef __attribute__((ext_vector_type(4))) float f32x4;    // MFMA C/D frag

// ---------------- helpers ----------------
__device__ __forceinline__ float wred(float v) {
  #pragma unroll
  for (int o = 32; o > 0; o >>= 1) v += __shfl_xor(v, o, 64);
  return v;
}
__device__ __forceinline__ float sigf(float x) { return 1.f / (1.f + expf(-x)); }

__device__ __forceinline__ void gl_lds16(const bf16* g, const bf16* lds) {
  // async global->LDS: lane i's 16B lands at wave-uniform LDS base + i*16
  __builtin_amdgcn_global_load_lds((const __attribute__((address_space(1))) void*)g,
                                   (__attribute__((address_space(3))) void*)lds,
                                   16, 0, 0);
}

// ---- batch GEMM: 128x128 tile, K=512, plain bf16 out (R7-verified core) ----
// C[M,N] = A[M,512] @ Bt[N,512]^T. Grid (N/128, M/128).
__global__ __launch_bounds__(256, 2)
void gemmpl(const bf16* __restrict__ A, const bf16* __restrict__ Bt,
            bf16* __restrict__ C, int ldc)
{
  __shared__ __align__(16) bf16 As[128 * 64];
  __shared__ __align__(16) bf16 Bs[128 * 64];
  const int tid  = threadIdx.x;
  const int wave = tid >> 6, lane = tid & 63;
  const int lm = lane & 15, q = lane >> 4;
  const int brow = blockIdx.y, bcol = blockIdx.x;
  const int wr = (wave >> 1) * 64, wc = (wave & 1) * 64;
  const int srow = lane >> 3, sslot = lane & 7;

  f32x4 acc[4][4];
  #pragma unroll
  for (int i = 0; i < 4; ++i)
    #pragma unroll
    for (int j = 0; j < 4; ++j) acc[i][j] = (f32x4){0.f, 0.f, 0.f, 0.f};

  for (int kb = 0; kb < 512; kb += 64) {
    #pragma unroll
    for (int j = 0; j < 4; ++j) {
      int ml = wave * 32 + j * 8 + srow;
      int cg = sslot ^ (ml & 7);
      gl_lds16(A + (size_t)(brow * 128 + ml) * 512 + kb + cg * 8,
               As + (wave * 4 + j) * 512);
      gl_lds16(Bt + (size_t)(bcol * 128 + ml) * 512 + kb + cg * 8,
               Bs + (wave * 4 + j) * 512);
    }
    __syncthreads();
    #pragma unroll
    for (int ks = 0; ks < 2; ++ks) {
      short8 af[4], bfr[4];
      #pragma unroll
      for (int i = 0; i < 4; ++i) {
        int cg = ks * 4 + q;
        int ml = wr + i * 16 + lm;
        af[i]  = *(const short8*)(As + ml * 64 + ((cg ^ (ml & 7)) * 8));
        int nl = wc + i * 16 + lm;
        bfr[i] = *(const short8*)(Bs + nl * 64 + ((cg ^ (nl & 7)) * 8));
      }
      #pragma unroll
      for (int i = 0; i < 4; ++i)
        #pragma unroll
        for (int j = 0; j < 4; ++j)
          acc[i][j] = __builtin_amdgcn_mfma_f32_16x16x32_bf16(af[i], bfr[j], acc[i][j], 0, 0, 0);
    }
    __syncthreads();
  }
  #pragma unroll
  for (int i = 0; i < 4; ++i) {
    int row0 = brow * 128 + wr + i * 16 + q * 4;
    #pragma unroll
    for (int j = 0; j < 4; ++j) {
      int col = bcol * 128 + wc + j * 16 + lm;
      #pragma unroll
      for (int p = 0; p < 4; ++p)
        C[(size_t)(row0 + p) * ldc + col] = __float2bfloat16(acc[i][j][p]);
    }
  }
}

// ---- GCN batch GEMM: all 8 steps, f32 A, dual source via blockIdx.z --------
// hfin[t*4096+n, z*256+col] = relu(Az[32768,128] @ Wgt[256,128]^T + b_gcn)
__global__ __launch_bounds__(256, 2)
void gcnk(const float* __restrict__ Ag, const float* __restrict__ Agi,
          const bf16* __restrict__ Wgt, const float* __restrict__ bias,
          bf16* __restrict__ out)
{
  __shared__ __align__(16) bf16 As[128 * 64];
  __shared__ __align__(16) bf16 Bs[128 * 64];
  const int tid  = threadIdx.x;
  const int wave = tid >> 6, lane = tid & 63;
  const int lm = lane & 15, q = lane >> 4;
  const int brow = blockIdx.y, bcol = blockIdx.x;
  const int z = blockIdx.z, cout = z * 256;
  const float* A = z ? Agi : Ag;
  const int wr = (wave >> 1) * 64, wc = (wave & 1) * 64;
  const int srow = lane >> 3, sslot = lane & 7;

  f32x4 acc[4][4];
  #pragma unroll
  for (int i = 0; i < 4; ++i)
    #pragma unroll
    for (int j = 0; j < 4; ++j) acc[i][j] = (f32x4){0.f, 0.f, 0.f, 0.f};

  for (int kb = 0; kb < 128; kb += 64) {
    #pragma unroll
    for (int j = 0; j < 4; ++j) {
      int ml = wave * 32 + j * 8 + srow;
      int cg = sslot ^ (ml & 7);
      const float* src = A + (size_t)(brow * 128 + ml) * 128 + kb + cg * 8;
      bf16 tmp[8];
      #pragma unroll
      for (int e = 0; e < 8; ++e) tmp[e] = __float2bfloat16(src[e]);
      *(short8*)(As + ml * 64 + sslot * 8) = *(const short8*)tmp;
      gl_lds16(Wgt + (size_t)(bcol * 128 + ml) * 128 + kb + cg * 8,   // no cout here!
               Bs + (wave * 4 + j) * 512);
    }
    __syncthreads();
    #pragma unroll
    for (int ks = 0; ks < 2; ++ks) {
      short8 af[4], bfr[4];
      #pragma unroll
      for (int i = 0; i < 4; ++i) {
        int cg = ks * 4 + q;
        int ml = wr + i * 16 + lm;
        af[i]  = *(const short8*)(As + ml * 64 + ((cg ^ (ml & 7)) * 8));
        int nl = wc + i * 16 + lm;
        bfr[i] = *(const short8*)(Bs + nl * 64 + ((cg ^ (nl & 7)) * 8));
      }
      #pragma unroll
      for (int i = 0; i < 4; ++i)
        #pragma unroll
        for (int j = 0; j < 4; ++j)
          acc[i][j] = __builtin_amdgcn_mfma_f32_16x16x32_bf16(af[i], bfr[j], acc[i][j], 0, 0, 0);
    }
    __syncthreads();
  }
  #pragma unroll
  for (int i = 0; i < 4; ++i) {
    int row0 = brow * 128 + wr + i * 16 + q * 4;
    #pragma unroll
    for (int j = 0; j < 4; ++j) {
      int col = bcol * 128 + wc + j * 16 + lm;
      float bv = bias[col];
      #pragma unroll
      for (int p = 0; p < 4; ++p) {
        float x = fmaxf(acc[i][j][p] + bv, 0.f);
        out[(size_t)(row0 + p) * 512 + cout + col] = __float2bfloat16(x);
      }
    }
  }
}

// ---- GRU step GEMM: 128x64 tile, K=512, 4 waves of 64x32 -------------------
// C = A[4096,512] @ Bt[N,512]^T + xpre + bias; grid (N/64, 32).
// mode 1 (zr, N=1024, ldx=1024): col<512 -> zh=f16(sigmoid); else rhb=bf16(sig*h)
// mode 2 (c,  N=512,  ldx=512):  h = z*h + (1-z)*tanh(x); hsb = bf16(h)
__global__ __launch_bounds__(256, 2)
void gruk(const bf16* __restrict__ A, const bf16* __restrict__ Bt,
          const bf16* __restrict__ xpre, int ldx,
          const float* __restrict__ bias, int mode,
          __half* __restrict__ zh, bf16* __restrict__ rhb,
          bf16* __restrict__ hsb)
{
  __shared__ __align__(16) bf16 As[128 * 64];
  __shared__ __align__(16) bf16 Bs[64 * 64];
  const int tid  = threadIdx.x;
  const int wave = tid >> 6, lane = tid & 63;
  const int lm = lane & 15, q = lane >> 4;
  const int brow = blockIdx.y, bcol = blockIdx.x;
  const int wr = (wave >> 1) * 64, wc = (wave & 1) * 32;
  const int srow = lane >> 3, sslot = lane & 7;

  f32x4 acc[4][2];
  #pragma unroll
  for (int i = 0; i < 4; ++i)
    #pragma unroll
    for (int j = 0; j < 2; ++j) acc[i][j] = (f32x4){0.f, 0.f, 0.f, 0.f};

  for (int kb = 0; kb < 512; kb += 64) {
    #pragma unroll
    for (int j = 0; j < 4; ++j) {
      int ml = wave * 32 + j * 8 + srow;
      int cg = sslot ^ (ml & 7);
      gl_lds16(A + (size_t)(brow * 128 + ml) * 512 + kb + cg * 8,
               As + (wave * 4 + j) * 512);
    }
    #pragma unroll
    for (int j = 0; j < 2; ++j) {
      int bl = wave * 16 + j * 8 + srow;
      int cg = sslot ^ (bl & 7);
      gl_lds16(Bt + (size_t)(bcol * 64 + bl) * 512 + kb + cg * 8,
               Bs + (wave * 2 + j) * 512);
    }
    __syncthreads();
    #pragma unroll
    for (int ks = 0; ks < 2; ++ks) {
      short8 af[4], bfr[2];
      #pragma unroll
      for (int i = 0; i < 4; ++i) {
        int cg = ks * 4 + q;
        int ml = wr + i * 16 + lm;
        af[i] = *(const short8*)(As + ml * 64 + ((cg ^ (ml & 7)) * 8));
      }
      #pragma unroll
      for (int j = 0; j < 2; ++j) {
        int cg = ks * 4 + q;
        int nl = wc + j * 16 + lm;
        bfr[j] = *(const short8*)(Bs + nl * 64 + ((cg ^ (nl & 7)) * 8));
      }
      #pragma unroll
      for (int i = 0; i < 4; ++i)
        #pragma unroll
        for (int j = 0; j < 2; ++j)
          acc[i][j] = __builtin_amdgcn_mfma_f32_16x16x32_bf16(af[i], bfr[j], acc[i][j], 0, 0, 0);
    }
    __syncthreads();
  }

  #pragma unroll
  for (int i = 0; i < 4; ++i) {
    int row0 = brow * 128 + wr + i * 16 + q * 4;
    #pragma unroll
    for (int j = 0; j < 2; ++j) {
      int col = bcol * 64 + wc + j * 16 + lm;
      float bv = bias[col];
      #pragma unroll
      for (int p = 0; p < 4; ++p) {
        int row = row0 + p;
        float x = acc[i][j][p] + (float)xpre[(size_t)row * ldx + col] + bv;
        if (mode == 1) {
          float s = sigf(x);
          if (col < 512) {
            zh[(size_t)row * 512 + col] = __float2half(s);
          } else {
            size_t o = (size_t)row * 512 + (col - 512);
            rhb[o] = __float2bfloat16(s * (float)hsb[o]);
          }
        } else {
          size_t o = (size_t)row * 512 + col;
          float z = __half2float(zh[o]);
          float h = z * (float)hsb[o] + (1.f - z) * tanhf(x);
          hsb[o] = __float2bfloat16(h);
        }
      }
    }
  }
}

// ---------------- small kernels (R7-verified) ----------------
__global__ void tcat(const float* __restrict__ X0, const float* __restrict__ X1,
                     int K0, int Ktot, int N, bf16* __restrict__ out) {
  int i = blockIdx.x * 256 + threadIdx.x;
  if (i >= N * Ktot) return;
  int n = i / Ktot, k = i % Ktot;
  float v = (k < K0) ? X0[(size_t)k * N + n] : X1[(size_t)(k - K0) * N + n];
  out[i] = __float2bfloat16(v);
}

__global__ void norm_lvec(const bf16* __restrict__ hsb, const float* __restrict__ Wl,
                          const float* __restrict__ bl, bf16* __restrict__ Htrb,
                          float* __restrict__ lv) {
  int w = threadIdx.x >> 6, lane = threadIdx.x & 63;
  int n = blockIdx.x * 4 + w;
  float x[8], ss = 0.f;
  #pragma unroll
  for (int j = 0; j < 8; ++j) {
    x[j] = (float)hsb[(size_t)n * 512 + lane * 8 + j];
    ss += x[j] * x[j];
  }
  ss = wred(ss);
  float inv = 1.f / fmaxf(sqrtf(ss), 1e-12f);
  float dot = 0.f;
  #pragma unroll
  for (int j = 0; j < 8; ++j) {
    float vv = x[j] * inv;
    Htrb[(size_t)n * 512 + lane * 8 + j] = __float2bfloat16(vv);
    dot += vv * Wl[lane * 8 + j];
  }
  dot = wred(dot);
  if (lane == 0) lv[n] = sigf(dot + bl[0]);
}

__global__ void hn_norm(const float* __restrict__ hv, float* __restrict__ hn) {
  int w = threadIdx.x >> 6, lane = threadIdx.x & 63;
  float x[8], ss = 0.f;
  #pragma unroll
  for (int j = 0; j < 8; ++j) { x[j] = hv[w * 512 + lane * 8 + j]; ss += x[j] * x[j]; }
  ss = wred(ss);
  float inv = 1.f / fmaxf(sqrtf(ss), 1e-12f);
  #pragma unroll
  for (int j = 0; j < 8; ++j) hn[w * 512 + lane * 8 + j] = x[j] * inv;
}

__global__ void mkfinal(const float* __restrict__ xf, const float* __restrict__ Wc,
                        const float* __restrict__ bc, const float* __restrict__ lv,
                        float* __restrict__ fin) {
  int i = blockIdx.x * 256 + threadIdx.x;
  int t = i >> 12, n = i & 4095;
  float g = bc[t];
  #pragma unroll
  for (int tt = 0; tt < 5; ++tt) g += xf[tt * 4096 + n] * Wc[tt * 4 + t];
  fin[i] = lv[n] * g;
}

__global__ void htf(const bf16* __restrict__ Htrb, const float* __restrict__ fin,
                    float* __restrict__ v) {
  int ch = blockIdx.x;
  int d = threadIdx.x;
  int n0 = ch * 64;
  float s0 = 0.f, s1 = 0.f, s2 = 0.f, s3 = 0.f;
  for (int i = 0; i < 64; ++i) {
    float hv = (float)Htrb[(size_t)(n0 + i) * 512 + d];
    s0 += hv * fin[n0 + i];
    s1 += hv * fin[4096 + n0 + i];
    s2 += hv * fin[8192 + n0 + i];
    s3 += hv * fin[12288 + n0 + i];
  }
  atomicAdd(&v[d], s0);
  atomicAdd(&v[512 + d], s1);
  atomicAdd(&v[1024 + d], s2);
  atomicAdd(&v[1536 + d], s3);
}

__global__ void attk(const bf16* __restrict__ Htrb, const float* __restrict__ v,
                     float* __restrict__ out) {
  int w = threadIdx.x >> 6, lane = threadIdx.x & 63;
  int n = blockIdx.x * 4 + w;
  float x[8];
  #pragma unroll
  for (int j = 0; j < 8; ++j) x[j] = (float)Htrb[(size_t)n * 512 + lane * 8 + j];
  #pragma unroll
  for (int t = 0; t < 4; ++t) {
    float s = 0.f;
    #pragma unroll
    for (int j = 0; j < 8; ++j) s += x[j] * v[t * 512 + lane * 8 + j];
    s = wred(s);
    if (lane == 0) out[t * 4096 + n] = s;
  }
}

__global__ void loff(const bf16* __restrict__ Htrb, const float* __restrict__ hn,
                     const int* __restrict__ ty, float* __restrict__ loffp) {
  int w = threadIdx.x >> 6, lane = threadIdx.x & 63;
  int t = blockIdx.y;
  int m = blockIdx.x * 4 + w;
  const int* row = ty + ((size_t)t * 2048 + m) * 18;
  int pi = row[1];
  float p[8], hv[8], c = 0.f;
  #pragma unroll
  for (int j = 0; j < 8; ++j) {
    p[j]  = (float)Htrb[(size_t)pi * 512 + lane * 8 + j];
    hv[j] = hn[t * 512 + lane * 8 + j];
    c += p[j] * hv[j];
  }
  c = wred(c);
  float a[8], sp = 0.f;
  #pragma unroll
  for (int j = 0; j < 8; ++j) { a[j] = p[j] - 2.f * c * hv[j]; sp += a[j] * p[j]; }
  sp = wred(sp);
  float acc = 0.f;
  for (int k = 0; k < 16; ++k) {
    int ni = row[2 + k];
    float sn = 0.f;
    #pragma unroll
    for (int j = 0; j < 8; ++j) sn += a[j] * (float)Htrb[(size_t)ni * 512 + lane * 8 + j];
    sn = wred(sn);
    acc += fmaxf(sn - sp + 0.5f, 0.f);
  }
  __shared__ float sbuf[4];
  if (lane == 0) sbuf[w] = acc;
  __syncthreads();
  if (threadIdx.x == 0)
    loffp[t * 512 + blockIdx.x] = sbuf[0] + sbuf[1] + sbuf[2] + sbuf[3];
}

__global__ void lleaf(const float* __restrict__ lv, const float* __restrict__ yl,
                      float* __restrict__ accum) {
  int i = blockIdx.x * 256 + threadIdx.x;
  float l = lv[i];
  float ym = 0.25f * (yl[i] + yl[4096 + i] + yl[8192 + i] + yl[12288 + i]);
  float term = fmaxf(l, 0.f) - l * ym + log1pf(expf(-fabsf(l)));
  float s = wred(term);
  __shared__ float sbuf[4];
  int w = threadIdx.x >> 6, lane = threadIdx.x & 63;
  if (lane == 0) sbuf[w] = s;
  __syncthreads();
  if (threadIdx.x == 0) atomicAdd(accum, sbuf[0] + sbuf[1] + sbuf[2] + sbuf[3]);
}

__global__ void fini(const float* __restrict__ loffp, const float* __restrict__ acc2,
                     float* __restrict__ out) {
  int tid = threadIdx.x, w = tid >> 6, lane = tid & 63;
  float s = 0.f;
  for (int i = tid; i < 2048; i += 256) s += loffp[i];
  s = wred(s);
  __shared__ float sb[4];
  if (lane == 0) sb[w] = s;
  __syncthreads();
  if (tid == 0) {
    out[16384] = (sb[0] + sb[1] + sb[2] + sb[3]) / (4.f * 2048.f * 16.f);
    out[16385] = acc2[1] / 4096.f;
  }
}

__global__ void wsprobe(float marker, float* out) {
  if (threadIdx.x == 0) out[0] = marker;
}

// ---------------- launch ----------------
extern "C" void kernel_launch(void* const* d_in, const int* in_sizes, int n_in,
                              void* d_out, int out_size, void* d_ws, size_t ws_size,
                              hipStream_t stream) {
  const float* x_feature   = (const float*)d_in[0];
  const float* x_graph     = (const float*)d_in[1];
  const float* x_graph_inv = (const float*)d_in[2];
  const int*   temp_y      = (const int*)d_in[3];
  const float* is_leaf     = (const float*)d_in[4];
  const float* W_gcn       = (const float*)d_in[5];
  const float* b_gcn       = (const float*)d_in[6];
  const float* Wx_zr       = (const float*)d_in[7];
  const float* Wh_zr       = (const float*)d_in[8];
  const float* b_zr        = (const float*)d_in[9];
  const float* Wx_c        = (const float*)d_in[10];
  const float* Wh_c        = (const float*)d_in[11];
  const float* b_c         = (const float*)d_in[12];
  const float* h_vecs      = (const float*)d_in[13];
  const float* W_leaf      = (const float*)d_in[14];
  const float* b_leaf      = (const float*)d_in[15];
  const float* W_conv      = (const float*)d_in[16];
  const float* b_conv      = (const float*)d_in[17];
  float* out = (float*)d_out;
  (void)in_sizes; (void)n_in; (void)out_size;

  const size_t NEED = 156000000;  // ~149 MB footprint; ws_size = 268 MB (R7 fill evidence)
  if (ws_size < NEED) {
    wsprobe<<<1, 64, 0, stream>>>(1000.f + (float)(ws_size >> 20), out);
    return;
  }

  char* ws = (char*)d_ws;
  size_t off = 0;
  auto alloc = [&](size_t bytes) -> void* {
    void* p = ws + off;
    off = (off + bytes + 255) & ~(size_t)255;
    return p;
  };
  bf16*   Whzrt = (bf16*)  alloc((size_t)1024 * 512 * 2);   // Wh_zr^T [1024,512]
  bf16*   Whct  = (bf16*)  alloc((size_t)512 * 512 * 2);    // Wh_c^T  [512,512]
  bf16*   Wxzrt = (bf16*)  alloc((size_t)1024 * 512 * 2);   // Wx_zr^T [1024,512]
  bf16*   Wxct  = (bf16*)  alloc((size_t)512 * 512 * 2);    // Wx_c^T  [512,512]
  bf16*   Wgt   = (bf16*)  alloc((size_t)256 * 128 * 2);    // W_gcn^T [256,128]
  bf16*   hfin  = (bf16*)  alloc((size_t)32768 * 512 * 2);  // h_final all steps (32 MB)
  bf16*   xzrp  = (bf16*)  alloc((size_t)32768 * 1024 * 2); // x@Wx_zr preact (64 MB)
  bf16*   xcp   = (bf16*)  alloc((size_t)32768 * 512 * 2);  // x@Wx_c preact (32 MB)
  bf16*   hsb   = (bf16*)  alloc((size_t)4096 * 512 * 2);   // GRU state
  bf16*   rhb   = (bf16*)  alloc((size_t)4096 * 512 * 2);   // r*h
  __half* zh    = (__half*)alloc((size_t)4096 * 512 * 2);   // z gate
  float*  lv    = (float*) alloc(4096 * 4);
  float*  hn    = (float*) alloc(4 * 512 * 4);
  float*  fin   = (float*) alloc(4 * 4096 * 4);
  float*  v     = (float*) alloc(4 * 512 * 4);              // contiguous with acc2
  float*  acc2  = (float*) alloc(256);
  float*  loffp = (float*) alloc(2048 * 4);
  bf16*   Htrb  = hfin;   // overlay: hfin dead after batch projections consumed

  hipMemsetAsync(hsb, 0, (size_t)4096 * 512 * 2, stream);   // h0 = 0
  hipMemsetAsync(v, 0, 4 * 512 * 4 + 256, stream);          // v + acc2

  // weight transposes (one-time)
  tcat<<<2048, 256, 0, stream>>>(Wh_zr, Wh_zr, 512, 512, 1024, Whzrt);
  tcat<<<1024, 256, 0, stream>>>(Wh_c, Wh_c, 512, 512, 512, Whct);
  tcat<<<2048, 256, 0, stream>>>(Wx_zr, Wx_zr, 512, 512, 1024, Wxzrt);
  tcat<<<1024, 256, 0, stream>>>(Wx_c, Wx_c, 512, 512, 512, Wxct);
  tcat<<<128, 256, 0, stream>>>(W_gcn, W_gcn, 128, 128, 256, Wgt);

  // batched (h-independent) GEMMs, full occupancy
  gcnk<<<dim3(2, 256, 2), 256, 0, stream>>>(x_graph, x_graph_inv, Wgt, b_gcn, hfin);
  gemmpl<<<dim3(8, 256), 256, 0, stream>>>(hfin, Wxzrt, xzrp, 1024);
  gemmpl<<<dim3(4, 256), 256, 0, stream>>>(hfin, Wxct, xcp, 512);

  // sequential GRU: only h@Wh remains per step (128x64 tiles, 512/256 blocks)
  for (int t = 0; t < 8; ++t) {
    const bf16* xz = xzrp + (size_t)t * 4096 * 1024;
    const bf16* xc = xcp + (size_t)t * 4096 * 512;
    gruk<<<dim3(16, 32), 256, 0, stream>>>(hsb, Whzrt, xz, 1024, b_zr, 1, zh, rhb, hsb);
    gruk<<<dim3(8, 32), 256, 0, stream>>>(rhb, Whct, xc, 512, b_c, 2, zh, nullptr, hsb);
  }

  // epilogue chain
  norm_lvec<<<1024, 256, 0, stream>>>(hsb, W_leaf, b_leaf, Htrb, lv);
  hn_norm<<<1, 256, 0, stream>>>(h_vecs, hn);
  mkfinal<<<64, 256, 0, stream>>>(x_feature, W_conv, b_conv, lv, fin);
  htf<<<64, 512, 0, stream>>>(Htrb, fin, v);
  attk<<<1024, 256, 0, stream>>>(Htrb, v, out);
  loff<<<dim3(512, 4), 256, 0, stream>>>(Htrb, hn, temp_y, loffp);
  lleaf<<<16, 256, 0, stream>>>(lv, is_leaf, &acc2[1]);
  fini<<<1, 256, 0, stream>>>(loffp, acc2, out);
}